// Round 1
// baseline (131.395 us; speedup 1.0000x reference)
//
#include <hip/hip_runtime.h>

#define IN_DIM 8192
#define OUT_DIM 8192
#define BATCH 2048

// ---------------------------------------------------------------------------
// Kernel 1: per-output-unit softmax over 16 weights, collapsed to 4 affine
// coefficients in the {1, a, b, ab} basis. SoA layout in workspace.
// gate_k coefficient table (const, a, b, ab):
//  g0:(0,0,0,0) g1:(0,0,0,1) g2:(0,1,0,-1) g3:(0,1,0,0) g4:(0,0,1,-1)
//  g5:(0,0,1,0) g6:(0,1,1,-2) g7:(0,1,1,-1) g8:(1,-1,-1,1) g9:(1,-1,-1,2)
//  g10:(1,0,-1,0) g11:(1,0,-1,1) g12:(1,-1,0,0) g13:(1,-1,0,1)
//  g14:(1,0,0,-1) g15:(1,0,0,0)
// ---------------------------------------------------------------------------
__global__ __launch_bounds__(256) void coeff_kernel(
    const float* __restrict__ w,
    float* __restrict__ c0, float* __restrict__ ca,
    float* __restrict__ cb, float* __restrict__ cab)
{
    int j = blockIdx.x * blockDim.x + threadIdx.x;
    if (j >= OUT_DIM) return;

    const float* wj = w + (size_t)j * 16;
    float wv[16];
    float m = -1e30f;
#pragma unroll
    for (int k = 0; k < 16; ++k) { wv[k] = wj[k]; m = fmaxf(m, wv[k]); }
    float s = 0.f;
#pragma unroll
    for (int k = 0; k < 16; ++k) { wv[k] = __expf(wv[k] - m); s += wv[k]; }
    float inv = 1.0f / s;
#pragma unroll
    for (int k = 0; k < 16; ++k) wv[k] *= inv;

    c0[j]  = wv[8] + wv[9] + wv[10] + wv[11] + wv[12] + wv[13] + wv[14] + wv[15];
    ca[j]  = wv[2] + wv[3] + wv[6] + wv[7] - wv[8] - wv[9] - wv[12] - wv[13];
    cb[j]  = wv[4] + wv[5] + wv[6] + wv[7] - wv[8] - wv[9] - wv[10] - wv[11];
    cab[j] = wv[1] - wv[2] - wv[4] - 2.f * wv[6] - wv[7]
           + wv[8] + 2.f * wv[9] + wv[11] + wv[13] - wv[14];
}

// ---------------------------------------------------------------------------
// Kernel 2: one block per batch row. Row of x (32 KB) staged in LDS, then
// each thread computes 4 consecutive outputs: coalesced int4 index loads,
// float4 coefficient loads, 8 LDS gathers, float4 store.
// ---------------------------------------------------------------------------
__global__ __launch_bounds__(256) void logic_kernel(
    const float* __restrict__ x,
    const int* __restrict__ idx_a,
    const int* __restrict__ idx_b,
    const float* __restrict__ c0, const float* __restrict__ ca,
    const float* __restrict__ cb, const float* __restrict__ cab,
    float* __restrict__ out)
{
    __shared__ float xrow[IN_DIM];

    const int i = blockIdx.x;
    const float4* xr4 = (const float4*)(x + (size_t)i * IN_DIM);
    float4* xs4 = (float4*)xrow;
    // 2048 float4s staged by 256 threads: 8 ds_write_b128 per thread, conflict-free.
#pragma unroll
    for (int k = threadIdx.x; k < IN_DIM / 4; k += 256) {
        xs4[k] = xr4[k];
    }
    __syncthreads();

    const int4*   ia4  = (const int4*)idx_a;
    const int4*   ib4  = (const int4*)idx_b;
    const float4* c04  = (const float4*)c0;
    const float4* ca4  = (const float4*)ca;
    const float4* cb4  = (const float4*)cb;
    const float4* cab4 = (const float4*)cab;
    float4* out4 = (float4*)(out + (size_t)i * OUT_DIM);

    for (int j4 = threadIdx.x; j4 < OUT_DIM / 4; j4 += 256) {
        int4 ia = ia4[j4];
        int4 ib = ib4[j4];
        float4 v0 = c04[j4], va = ca4[j4], vb = cb4[j4], vab = cab4[j4];

        float a0 = xrow[ia.x], b0 = xrow[ib.x];
        float a1 = xrow[ia.y], b1 = xrow[ib.y];
        float a2 = xrow[ia.z], b2 = xrow[ib.z];
        float a3 = xrow[ia.w], b3 = xrow[ib.w];

        float4 o;
        o.x = v0.x + va.x * a0 + vb.x * b0 + vab.x * (a0 * b0);
        o.y = v0.y + va.y * a1 + vb.y * b1 + vab.y * (a1 * b1);
        o.z = v0.z + va.z * a2 + vb.z * b2 + vab.z * (a2 * b2);
        o.w = v0.w + va.w * a3 + vb.w * b3 + vab.w * (a3 * b3);
        out4[j4] = o;
    }
}

extern "C" void kernel_launch(void* const* d_in, const int* in_sizes, int n_in,
                              void* d_out, int out_size, void* d_ws, size_t ws_size,
                              hipStream_t stream)
{
    const float* x       = (const float*)d_in[0];  // (2048, 8192) fp32
    const float* weights = (const float*)d_in[1];  // (8192, 16)   fp32
    const int*   idx_a   = (const int*)d_in[2];    // (8192,) int
    const int*   idx_b   = (const int*)d_in[3];    // (8192,) int
    float* out = (float*)d_out;                    // (2048, 8192) fp32

    float* wsF = (float*)d_ws;
    float* c0  = wsF;
    float* ca  = wsF + OUT_DIM;
    float* cb  = wsF + 2 * OUT_DIM;
    float* cab = wsF + 3 * OUT_DIM;

    coeff_kernel<<<OUT_DIM / 256, 256, 0, stream>>>(weights, c0, ca, cb, cab);
    logic_kernel<<<BATCH, 256, 0, stream>>>(x, idx_a, idx_b, c0, ca, cb, cab, out);
}

// Round 3
// 123.836 us; speedup vs baseline: 1.0610x; 1.0610x over previous
//
#include <hip/hip_runtime.h>

#define IN_DIM 8192
#define OUT_DIM 8192
#define BATCH 2048
#define TPB 512            // 8 waves/block; 32KB LDS -> 4 blocks/CU = 32 waves/CU (occupancy cap)
#define JITER (OUT_DIM / 4 / TPB)   // 4 fully-unrolled j-iterations per thread

typedef float fvec4 __attribute__((ext_vector_type(4)));   // native vector for nontemporal builtin

// ---------------------------------------------------------------------------
// Kernel 1: per-output-unit softmax over 16 weights, collapsed to 4 affine
// coefficients in the {1, a, b, ab} basis. SoA layout in workspace.
// ---------------------------------------------------------------------------
__global__ __launch_bounds__(256) void coeff_kernel(
    const float* __restrict__ w,
    float* __restrict__ c0, float* __restrict__ ca,
    float* __restrict__ cb, float* __restrict__ cab)
{
    int j = blockIdx.x * blockDim.x + threadIdx.x;
    if (j >= OUT_DIM) return;

    const float* wj = w + (size_t)j * 16;
    float wv[16];
    float m = -1e30f;
#pragma unroll
    for (int k = 0; k < 16; ++k) { wv[k] = wj[k]; m = fmaxf(m, wv[k]); }
    float s = 0.f;
#pragma unroll
    for (int k = 0; k < 16; ++k) { wv[k] = __expf(wv[k] - m); s += wv[k]; }
    float inv = 1.0f / s;
#pragma unroll
    for (int k = 0; k < 16; ++k) wv[k] *= inv;

    c0[j]  = wv[8] + wv[9] + wv[10] + wv[11] + wv[12] + wv[13] + wv[14] + wv[15];
    ca[j]  = wv[2] + wv[3] + wv[6] + wv[7] - wv[8] - wv[9] - wv[12] - wv[13];
    cb[j]  = wv[4] + wv[5] + wv[6] + wv[7] - wv[8] - wv[9] - wv[10] - wv[11];
    cab[j] = wv[1] - wv[2] - wv[4] - 2.f * wv[6] - wv[7]
           + wv[8] + 2.f * wv[9] + wv[11] + wv[13] - wv[14];
}

// ---------------------------------------------------------------------------
// Kernel 2: one block per batch row. 512 threads, 32KB LDS row stage.
// All global loads for the whole row batched up-front (max ILP, one latency
// exposure), then all LDS gathers, then FMA + nontemporal float4 store.
// ---------------------------------------------------------------------------
__global__ __launch_bounds__(TPB) void logic_kernel(
    const float* __restrict__ x,
    const int* __restrict__ idx_a,
    const int* __restrict__ idx_b,
    const float* __restrict__ c0, const float* __restrict__ ca,
    const float* __restrict__ cb, const float* __restrict__ cab,
    float* __restrict__ out)
{
    __shared__ float xrow[IN_DIM];

    const int i = blockIdx.x;
    const float4* xr4 = (const float4*)(x + (size_t)i * IN_DIM);
    float4* xs4 = (float4*)xrow;
    // 2048 float4s staged by 512 threads: 4 ds_write_b128 each, conflict-free.
#pragma unroll
    for (int k = 0; k < IN_DIM / 4 / TPB; ++k) {
        int idx = k * TPB + threadIdx.x;
        xs4[idx] = xr4[idx];
    }

    const int4*   ia4  = (const int4*)idx_a;
    const int4*   ib4  = (const int4*)idx_b;
    const float4* c04  = (const float4*)c0;
    const float4* ca4  = (const float4*)ca;
    const float4* cb4  = (const float4*)cb;
    const float4* cab4 = (const float4*)cab;
    fvec4* out4 = (fvec4*)(out + (size_t)i * OUT_DIM);

    // Batch ALL global loads (independent of the LDS stage) before the barrier:
    // 2 int4 + 4 float4 per iter x 4 iters ~= 96 VGPRs of payload in flight.
    int4   ia[JITER], ib[JITER];
    float4 v0[JITER], va[JITER], vb[JITER], vab[JITER];
#pragma unroll
    for (int it = 0; it < JITER; ++it) {
        int j4 = it * TPB + threadIdx.x;           // coalesced
        ia[it]  = ia4[j4];
        ib[it]  = ib4[j4];
        v0[it]  = c04[j4];
        va[it]  = ca4[j4];
        vb[it]  = cb4[j4];
        vab[it] = cab4[j4];
    }

    __syncthreads();

#pragma unroll
    for (int it = 0; it < JITER; ++it) {
        int j4 = it * TPB + threadIdx.x;

        float a0 = xrow[ia[it].x], b0 = xrow[ib[it].x];
        float a1 = xrow[ia[it].y], b1 = xrow[ib[it].y];
        float a2 = xrow[ia[it].z], b2 = xrow[ib[it].z];
        float a3 = xrow[ia[it].w], b3 = xrow[ib[it].w];

        fvec4 o;
        o.x = v0[it].x + va[it].x * a0 + vb[it].x * b0 + vab[it].x * (a0 * b0);
        o.y = v0[it].y + va[it].y * a1 + vb[it].y * b1 + vab[it].y * (a1 * b1);
        o.z = v0[it].z + va[it].z * a2 + vb[it].z * b2 + vab[it].z * (a2 * b2);
        o.w = v0[it].w + va[it].w * a3 + vb[it].w * b3 + vab[it].w * (a3 * b3);
        __builtin_nontemporal_store(o, &out4[j4]);
    }
}

extern "C" void kernel_launch(void* const* d_in, const int* in_sizes, int n_in,
                              void* d_out, int out_size, void* d_ws, size_t ws_size,
                              hipStream_t stream)
{
    const float* x       = (const float*)d_in[0];  // (2048, 8192) fp32
    const float* weights = (const float*)d_in[1];  // (8192, 16)   fp32
    const int*   idx_a   = (const int*)d_in[2];    // (8192,) int
    const int*   idx_b   = (const int*)d_in[3];    // (8192,) int
    float* out = (float*)d_out;                    // (2048, 8192) fp32

    float* wsF = (float*)d_ws;
    float* c0  = wsF;
    float* ca  = wsF + OUT_DIM;
    float* cb  = wsF + 2 * OUT_DIM;
    float* cab = wsF + 3 * OUT_DIM;

    coeff_kernel<<<OUT_DIM / 256, 256, 0, stream>>>(weights, c0, ca, cb, cab);
    logic_kernel<<<BATCH, TPB, 0, stream>>>(x, idx_a, idx_b, c0, ca, cb, cab, out);
}